// Round 2
// baseline (1740.290 us; speedup 1.0000x reference)
//
#include <hip/hip_runtime.h>
#include <stdint.h>

#define DEVI __device__ __forceinline__

typedef unsigned short u16;
typedef __attribute__((ext_vector_type(8))) unsigned short u16x8;
typedef __attribute__((ext_vector_type(4))) float f32x4;
typedef __attribute__((ext_vector_type(8))) _Float16 f16x8;

static constexpr int NT = 4096;   // tokens
static constexpr int D  = 512;    // channels per head
static constexpr int NH = 4;      // heads

DEVI u16 f2h(float f) {
  _Float16 h = (_Float16)f;        // v_cvt_f16_f32, RNE
  union { _Float16 h; u16 u; } v; v.h = h;
  return v.u;
}

DEVI void gld_lds16(const u16* g, u16* l) {
  __builtin_amdgcn_global_load_lds((const __attribute__((address_space(1))) void*)g,
                                   (__attribute__((address_space(3))) void*)l, 16, 0, 0);
}

enum { OUT_F32 = 0, OUT_ADD = 1, OUT_F16 = 2, OUT_RES = 3 };

// C[M,N] = A[M,K] @ B[N,K]^T  (both fp16, acc f32). 128x128 tile, BK=32, 4 waves.
template<int OUT>
__global__ __launch_bounds__(256)
void gemm_bt(const u16* __restrict__ A, int lda,
             const u16* __restrict__ B, int ldb,
             void* __restrict__ Cp, int ldc,
             const float* __restrict__ res,
             int M, int N, int K)
{
  __shared__ u16 As[128 * 32];
  __shared__ u16 Bs[128 * 32];
  const int tid = threadIdx.x;
  const int lane = tid & 63, w = tid >> 6;
  const int wr = w >> 1, wc = w & 1;
  const int m0 = blockIdx.y * 128, n0 = blockIdx.x * 128;

  f32x4 acc[4][4] = {};

  for (int k0 = 0; k0 < K; k0 += 32) {
    __syncthreads();
#pragma unroll
    for (int p = 0; p < 2; ++p) {
      int id = p * 256 + tid;
      int row = id >> 2, q = id & 3;
      gld_lds16(A + (size_t)(m0 + row) * lda + k0 + q * 8, As + id * 8);
      gld_lds16(B + (size_t)(n0 + row) * ldb + k0 + q * 8, Bs + id * 8);
    }
    __syncthreads();
    f16x8 af[4], bfv[4];
#pragma unroll
    for (int i = 0; i < 4; ++i)
      af[i] = *(const f16x8*)(As + (wr * 64 + i * 16 + (lane & 15)) * 32 + (lane >> 4) * 8);
#pragma unroll
    for (int i = 0; i < 4; ++i)
      bfv[i] = *(const f16x8*)(Bs + (wc * 64 + i * 16 + (lane & 15)) * 32 + (lane >> 4) * 8);
#pragma unroll
    for (int i = 0; i < 4; ++i)
#pragma unroll
      for (int j = 0; j < 4; ++j)
        acc[i][j] = __builtin_amdgcn_mfma_f32_16x16x32_f16(af[i], bfv[j], acc[i][j], 0, 0, 0);
  }

#pragma unroll
  for (int i = 0; i < 4; ++i) {
    int r0 = m0 + wr * 64 + i * 16 + (lane >> 4) * 4;
#pragma unroll
    for (int j = 0; j < 4; ++j) {
      int c = n0 + wc * 64 + j * 16 + (lane & 15);
#pragma unroll
      for (int e = 0; e < 4; ++e) {
        size_t idx = (size_t)(r0 + e) * ldc + c;
        float v = acc[i][j][e];
        if (OUT == OUT_F32) ((float*)Cp)[idx] = v;
        if (OUT == OUT_ADD) ((float*)Cp)[idx] += v;
        if (OUT == OUT_F16) ((u16*)Cp)[idx] = f2h(v);
        if (OUT == OUT_RES) ((float*)Cp)[idx] = res[idx] + v;
      }
    }
  }
}

// C[M,N] += (1/(4*rowl[m])) * exp(S[m,k]-rowm[m]) @ B[N,K]^T
// A staged from f32 S with fused exp into padded LDS; B via global_load_lds.
__global__ __launch_bounds__(256)
void gemm_pv(const float* __restrict__ S, int ldS,
             const u16* __restrict__ B, int ldb,
             float* __restrict__ C, int ldc,
             const float* __restrict__ rowm, const float* __restrict__ rowl,
             int M, int N, int K)
{
  __shared__ u16 As[128 * 40];   // padded: row stride 40 elems (80B) -> free 2-way on frag reads
  __shared__ u16 Bs[128 * 32];
  __shared__ float rmv[128];
  const int tid = threadIdx.x;
  const int lane = tid & 63, w = tid >> 6;
  const int wr = w >> 1, wc = w & 1;
  const int m0 = blockIdx.y * 128, n0 = blockIdx.x * 128;

  if (tid < 128) rmv[tid] = rowm[m0 + tid];

  f32x4 acc[4][4] = {};

  for (int k0 = 0; k0 < K; k0 += 32) {
    __syncthreads();
#pragma unroll
    for (int p = 0; p < 2; ++p) {        // B tile: async direct-to-LDS
      int id = p * 256 + tid;
      int row = id >> 2, q = id & 3;
      gld_lds16(B + (size_t)(n0 + row) * ldb + k0 + q * 8, Bs + id * 8);
    }
#pragma unroll
    for (int p = 0; p < 2; ++p) {        // A tile: f32 S -> exp -> f16 -> LDS
      int flat = p * 2048 + tid * 8;
      int row = flat >> 5, k = flat & 31;
      const float* src = S + (size_t)(m0 + row) * ldS + k0 + k;
      f32x4 v0 = *(const f32x4*)src;
      f32x4 v1 = *(const f32x4*)(src + 4);
      float mm = rmv[row];
      u16x8 pk;
      pk[0] = f2h(__expf(v0[0] - mm)); pk[1] = f2h(__expf(v0[1] - mm));
      pk[2] = f2h(__expf(v0[2] - mm)); pk[3] = f2h(__expf(v0[3] - mm));
      pk[4] = f2h(__expf(v1[0] - mm)); pk[5] = f2h(__expf(v1[1] - mm));
      pk[6] = f2h(__expf(v1[2] - mm)); pk[7] = f2h(__expf(v1[3] - mm));
      *(u16x8*)(As + row * 40 + k) = pk;
    }
    __syncthreads();
    f16x8 af[4], bfv[4];
#pragma unroll
    for (int i = 0; i < 4; ++i)
      af[i] = *(const f16x8*)(As + (wr * 64 + i * 16 + (lane & 15)) * 40 + (lane >> 4) * 8);
#pragma unroll
    for (int i = 0; i < 4; ++i)
      bfv[i] = *(const f16x8*)(Bs + (wc * 64 + i * 16 + (lane & 15)) * 32 + (lane >> 4) * 8);
#pragma unroll
    for (int i = 0; i < 4; ++i)
#pragma unroll
      for (int j = 0; j < 4; ++j)
        acc[i][j] = __builtin_amdgcn_mfma_f32_16x16x32_f16(af[i], bfv[j], acc[i][j], 0, 0, 0);
  }

#pragma unroll
  for (int i = 0; i < 4; ++i) {
    int r0 = m0 + wr * 64 + i * 16 + (lane >> 4) * 4;
#pragma unroll
    for (int e = 0; e < 4; ++e) {
      float inv = 1.0f / (4.0f * rowl[r0 + e]);   // 1/4 = head mean
#pragma unroll
      for (int j = 0; j < 4; ++j) {
        int c = n0 + wc * 64 + j * 16 + (lane & 15);
        C[(size_t)(r0 + e) * ldc + c] += acc[i][j][e] * inv;
      }
    }
  }
}

// per-row max and sum(exp(x-max)) over ncols f32
__global__ __launch_bounds__(256)
void row_stats(const float* __restrict__ S, int ld,
               float* __restrict__ rowm, float* __restrict__ rowl, int ncols)
{
  int r = blockIdx.x;
  const float* row = S + (size_t)r * ld;
  int tid = threadIdx.x;
  float m = -3.0e38f;
  for (int c = tid * 4; c < ncols; c += 1024) {
    f32x4 v = *(const f32x4*)(row + c);
    m = fmaxf(m, fmaxf(fmaxf(v[0], v[1]), fmaxf(v[2], v[3])));
  }
#pragma unroll
  for (int o = 32; o; o >>= 1) m = fmaxf(m, __shfl_xor(m, o));
  __shared__ float sm[4], sl[4];
  if ((tid & 63) == 0) sm[tid >> 6] = m;
  __syncthreads();
  m = fmaxf(fmaxf(sm[0], sm[1]), fmaxf(sm[2], sm[3]));
  float l = 0.f;
  for (int c = tid * 4; c < ncols; c += 1024) {
    f32x4 v = *(const f32x4*)(row + c);
    l += __expf(v[0] - m) + __expf(v[1] - m) + __expf(v[2] - m) + __expf(v[3] - m);
  }
#pragma unroll
  for (int o = 32; o; o >>= 1) l += __shfl_xor(l, o);
  if ((tid & 63) == 0) sl[tid >> 6] = l;
  __syncthreads();
  if (tid == 0) { rowm[r] = m; rowl[r] = sl[0] + sl[1] + sl[2] + sl[3]; }
}

__global__ __launch_bounds__(256)
void cast_f32_f16(const float* __restrict__ in, u16* __restrict__ out, int n)
{
  int i = (blockIdx.x * 256 + threadIdx.x) * 8;
  if (i >= n) return;
  f32x4 a = *(const f32x4*)(in + i), b = *(const f32x4*)(in + i + 4);
  u16x8 s;
  s[0] = f2h(a[0]); s[1] = f2h(a[1]); s[2] = f2h(a[2]); s[3] = f2h(a[3]);
  s[4] = f2h(b[0]); s[5] = f2h(b[1]); s[6] = f2h(b[2]); s[7] = f2h(b[3]);
  *(u16x8*)(out + i) = s;
}

// out[c][r] = f16(in[r][c]);  64x64 tiles
__global__ __launch_bounds__(256)
void transpose_cast_f32(const float* __restrict__ in, int ldi,
                        u16* __restrict__ out, int ldo)
{
  __shared__ u16 t[64][72];
  int r0 = blockIdx.x * 64, c0 = blockIdx.y * 64;
  int t8 = threadIdx.x & 7, rr = threadIdx.x >> 3;
#pragma unroll
  for (int p = 0; p < 2; ++p) {
    int r = rr + p * 32;
    const float* src = in + (size_t)(r0 + r) * ldi + c0 + t8 * 8;
    f32x4 a = *(const f32x4*)src, b = *(const f32x4*)(src + 4);
    u16x8 s;
    s[0] = f2h(a[0]); s[1] = f2h(a[1]); s[2] = f2h(a[2]); s[3] = f2h(a[3]);
    s[4] = f2h(b[0]); s[5] = f2h(b[1]); s[6] = f2h(b[2]); s[7] = f2h(b[3]);
    *(u16x8*)&t[r][t8 * 8] = s;
  }
  __syncthreads();
#pragma unroll
  for (int p = 0; p < 2; ++p) {
    int c = rr + p * 32;
    u16x8 s;
#pragma unroll
    for (int j = 0; j < 8; ++j) s[j] = t[t8 * 8 + j][c];
    *(u16x8*)(out + (size_t)(c0 + c) * ldo + r0 + t8 * 8) = s;
  }
}

__global__ __launch_bounds__(256)
void transpose_f16(const u16* __restrict__ in, int ldi,
                   u16* __restrict__ out, int ldo)
{
  __shared__ u16 t[64][72];
  int r0 = blockIdx.x * 64, c0 = blockIdx.y * 64;
  int t8 = threadIdx.x & 7, rr = threadIdx.x >> 3;
#pragma unroll
  for (int p = 0; p < 2; ++p) {
    int r = rr + p * 32;
    *(u16x8*)&t[r][t8 * 8] = *(const u16x8*)(in + (size_t)(r0 + r) * ldi + c0 + t8 * 8);
  }
  __syncthreads();
#pragma unroll
  for (int p = 0; p < 2; ++p) {
    int c = rr + p * 32;
    u16x8 s;
#pragma unroll
    for (int j = 0; j < 8; ++j) s[j] = t[t8 * 8 + j][c];
    *(u16x8*)(out + (size_t)(c0 + c) * ldo + r0 + t8 * 8) = s;
  }
}

extern "C" void kernel_launch(void* const* d_in, const int* in_sizes, int n_in,
                              void* d_out, int out_size, void* d_ws, size_t ws_size,
                              hipStream_t stream)
{
  const float* x_k    = (const float*)d_in[0];
  const float* x_q    = (const float*)d_in[1];
  const float* k_w    = (const float*)d_in[2];
  const float* q_w    = (const float*)d_in[3];
  const float* attn_w = (const float*)d_in[4];
  const float* proj_w = (const float*)d_in[5];
  float* out0 = (float*)d_out;
  float* out1 = out0 + (size_t)NT * D;

  char* wptr = (char*)d_ws;
  auto alloc = [&](size_t bytes) { char* p = wptr; wptr += (bytes + 255) & ~(size_t)255; return p; };
  u16*   xkb  = (u16*)  alloc((size_t)NT * D * 2);
  u16*   xqb  = (u16*)  alloc((size_t)NT * D * 2);
  u16*   kwb  = (u16*)  alloc((size_t)NH * D * D * 2);
  u16*   qwb  = (u16*)  alloc((size_t)NH * D * D * 2);
  u16*   Abf  = (u16*)  alloc((size_t)NH * D * D * 2);
  u16*   ATbf = (u16*)  alloc((size_t)NH * D * D * 2);
  u16*   pb   = (u16*)  alloc((size_t)D * D * 2);
  u16*   pbT  = (u16*)  alloc((size_t)D * D * 2);
  u16*   XK   = (u16*)  alloc((size_t)NT * D * 2);
  u16*   XQ   = (u16*)  alloc((size_t)NT * D * 2);
  u16*   XKT  = (u16*)  alloc((size_t)NT * D * 2);
  u16*   XQT  = (u16*)  alloc((size_t)NT * D * 2);
  u16*   Kp   = (u16*)  alloc((size_t)NT * D * 2);   // reused as aggk_f16
  u16*   Kpp  = (u16*)  alloc((size_t)NT * D * 2);   // reused as aggq_f16
  float* aggk = (float*)alloc((size_t)NT * D * 4);
  float* aggq = (float*)alloc((size_t)NT * D * 4);   // contiguous with aggk
  float* rowm = (float*)alloc((size_t)NT * 4);
  float* rowl = (float*)alloc((size_t)NT * 4);
  float* S    = (float*)alloc((size_t)NT * NT * 4);

  // ---- casts ----
  cast_f32_f16<<<NT * D / 2048, 256, 0, stream>>>(x_k, xkb, NT * D);
  cast_f32_f16<<<NT * D / 2048, 256, 0, stream>>>(x_q, xqb, NT * D);
  cast_f32_f16<<<NH * D * D / 2048, 256, 0, stream>>>(k_w, kwb, NH * D * D);
  cast_f32_f16<<<NH * D * D / 2048, 256, 0, stream>>>(q_w, qwb, NH * D * D);
  cast_f32_f16<<<NH * D * D / 2048, 256, 0, stream>>>(attn_w, Abf, NH * D * D);
  cast_f32_f16<<<D * D / 2048, 256, 0, stream>>>(proj_w, pb, D * D);
  for (int h = 0; h < NH; ++h)
    transpose_cast_f32<<<dim3(D / 64, D / 64), 256, 0, stream>>>(attn_w + (size_t)h * D * D, D,
                                                                 ATbf + (size_t)h * D * D, D);
  transpose_cast_f32<<<dim3(D / 64, D / 64), 256, 0, stream>>>(proj_w, D, pbT, D);

  hipMemsetAsync(aggk, 0, (size_t)NT * D * 4 * 2, stream);   // aggk + aggq

  // ---- per-head pipeline ----
  for (int h = 0; h < NH; ++h) {
    const u16* kwh = kwb + (size_t)h * D * D;
    const u16* qwh = qwb + (size_t)h * D * D;
    const u16* Ah  = Abf + (size_t)h * D * D;
    const u16* ATh = ATbf + (size_t)h * D * D;

    gemm_bt<OUT_F16><<<dim3(D / 128, NT / 128), 256, 0, stream>>>(xkb, D, kwh, D, XK, D, nullptr, NT, D, D);
    gemm_bt<OUT_F16><<<dim3(D / 128, NT / 128), 256, 0, stream>>>(xqb, D, qwh, D, XQ, D, nullptr, NT, D, D);
    transpose_f16<<<dim3(NT / 64, D / 64), 256, 0, stream>>>(XK, D, XKT, NT);
    transpose_f16<<<dim3(NT / 64, D / 64), 256, 0, stream>>>(XQ, D, XQT, NT);
    gemm_bt<OUT_F16><<<dim3(D / 128, NT / 128), 256, 0, stream>>>(XQ, D, Ah,  D, Kp,  D, nullptr, NT, D, D);
    gemm_bt<OUT_F16><<<dim3(D / 128, NT / 128), 256, 0, stream>>>(XK, D, ATh, D, Kpp, D, nullptr, NT, D, D);

    // dir1: S1 = XK @ Kp^T ; aggk += rowsoftmax(S1) @ XQ
    gemm_bt<OUT_F32><<<dim3(NT / 128, NT / 128), 256, 0, stream>>>(XK, D, Kp, D, S, NT, nullptr, NT, NT, D);
    row_stats<<<NT, 256, 0, stream>>>(S, NT, rowm, rowl, NT);
    gemm_pv<<<dim3(D / 128, NT / 128), 256, 0, stream>>>(S, NT, XQT, NT, aggk, D, rowm, rowl, NT, D, NT);

    // dir2: S2 = XQ @ Kpp^T (= S1^T) ; aggq += rowsoftmax(S2) @ XK
    gemm_bt<OUT_F32><<<dim3(NT / 128, NT / 128), 256, 0, stream>>>(XQ, D, Kpp, D, S, NT, nullptr, NT, NT, D);
    row_stats<<<NT, 256, 0, stream>>>(S, NT, rowm, rowl, NT);
    gemm_pv<<<dim3(D / 128, NT / 128), 256, 0, stream>>>(S, NT, XKT, NT, aggq, D, rowm, rowl, NT, D, NT);
  }

  // ---- final projections + residual ----
  cast_f32_f16<<<NT * D / 2048, 256, 0, stream>>>(aggk, Kp,  NT * D);
  cast_f32_f16<<<NT * D / 2048, 256, 0, stream>>>(aggq, Kpp, NT * D);
  gemm_bt<OUT_RES><<<dim3(D / 128, NT / 128), 256, 0, stream>>>(Kp,  D, pb,  D, out0, D, x_k, NT, D, D);
  gemm_bt<OUT_RES><<<dim3(D / 128, NT / 128), 256, 0, stream>>>(Kpp, D, pbT, D, out1, D, x_q, NT, D, D);
}

// Round 3
// 1188.887 us; speedup vs baseline: 1.4638x; 1.4638x over previous
//
#include <hip/hip_runtime.h>
#include <stdint.h>

#define DEVI __device__ __forceinline__

typedef unsigned short u16;
typedef unsigned int u32;
typedef __attribute__((ext_vector_type(4))) unsigned short u16x4;
typedef __attribute__((ext_vector_type(8))) unsigned short u16x8;
typedef __attribute__((ext_vector_type(4))) float f32x4;
typedef __attribute__((ext_vector_type(8))) _Float16 f16x8;

static constexpr int NT = 4096;   // tokens
static constexpr int D  = 512;    // channels per head
static constexpr int NH = 4;      // heads

DEVI u16 f2h(float f) {
  _Float16 h = (_Float16)f;
  union { _Float16 h; u16 u; } v; v.h = h;
  return v.u;
}

// order-preserving float<->uint for atomicMax on floats
DEVI u32 enc_ord(float f) {
  u32 u = __float_as_uint(f);
  return (u & 0x80000000u) ? ~u : (u | 0x80000000u);
}
DEVI float dec_ord(u32 k) {
  u32 u = (k & 0x80000000u) ? (k ^ 0x80000000u) : ~k;
  return __uint_as_float(u);
}

DEVI void gld_lds16(const u16* g, u16* l) {
  __builtin_amdgcn_global_load_lds((const __attribute__((address_space(1))) void*)g,
                                   (__attribute__((address_space(3))) void*)l, 16, 0, 0);
}

enum { OUT_F32 = 0, OUT_F16 = 2, OUT_RES = 3 };

// C[M,N] = A[M,K] @ B[N,K]^T  (f16 in, f32 acc). 128x128 tile, BK=32, 4 waves.
// Optional batch via blockIdx.z with element strides zsA/zsB/zsC.
template<int OUT>
__global__ __launch_bounds__(256)
void gemm_bt(const u16* __restrict__ A, int lda, size_t zsA,
             const u16* __restrict__ B, int ldb, size_t zsB,
             void* __restrict__ Cp, int ldc, size_t zsC,
             const float* __restrict__ res, int K)
{
  __shared__ u16 As[128 * 32];
  __shared__ u16 Bs[128 * 32];
  A += blockIdx.z * zsA;
  B += blockIdx.z * zsB;
  const int tid = threadIdx.x;
  const int lane = tid & 63, w = tid >> 6;
  const int wr = w >> 1, wc = w & 1;
  const int m0 = blockIdx.y * 128, n0 = blockIdx.x * 128;

  f32x4 acc[4][4] = {};

  for (int k0 = 0; k0 < K; k0 += 32) {
    __syncthreads();
#pragma unroll
    for (int p = 0; p < 2; ++p) {
      int id = p * 256 + tid;
      int row = id >> 2, q = id & 3;
      gld_lds16(A + (size_t)(m0 + row) * lda + k0 + q * 8, As + id * 8);
      gld_lds16(B + (size_t)(n0 + row) * ldb + k0 + q * 8, Bs + id * 8);
    }
    __syncthreads();
    f16x8 af[4], bfv[4];
#pragma unroll
    for (int i = 0; i < 4; ++i)
      af[i] = *(const f16x8*)(As + (wr * 64 + i * 16 + (lane & 15)) * 32 + (lane >> 4) * 8);
#pragma unroll
    for (int i = 0; i < 4; ++i)
      bfv[i] = *(const f16x8*)(Bs + (wc * 64 + i * 16 + (lane & 15)) * 32 + (lane >> 4) * 8);
#pragma unroll
    for (int i = 0; i < 4; ++i)
#pragma unroll
      for (int j = 0; j < 4; ++j)
        acc[i][j] = __builtin_amdgcn_mfma_f32_16x16x32_f16(af[i], bfv[j], acc[i][j], 0, 0, 0);
  }

#pragma unroll
  for (int i = 0; i < 4; ++i) {
    int r0 = m0 + wr * 64 + i * 16 + (lane >> 4) * 4;
#pragma unroll
    for (int j = 0; j < 4; ++j) {
      int c = n0 + wc * 64 + j * 16 + (lane & 15);
#pragma unroll
      for (int e = 0; e < 4; ++e) {
        size_t idx = blockIdx.z * zsC + (size_t)(r0 + e) * ldc + c;
        float v = acc[i][j][e];
        if (OUT == OUT_F32) ((float*)Cp)[idx] = v;
        if (OUT == OUT_F16) ((u16*)Cp)[idx] = f2h(v);
        if (OUT == OUT_RES) ((float*)Cp)[idx] = res[idx] + v;
      }
    }
  }
}

// C[M,N] += (0.25/l[m]) * (P[M,K] @ B[N,K]^T)   P,B f16
__global__ __launch_bounds__(256)
void gemm_ps(const u16* __restrict__ P, int lda,
             const u16* __restrict__ B, int ldb,
             float* __restrict__ C, int ldc,
             const float* __restrict__ l, int K)
{
  __shared__ u16 As[128 * 32];
  __shared__ u16 Bs[128 * 32];
  const int tid = threadIdx.x;
  const int lane = tid & 63, w = tid >> 6;
  const int wr = w >> 1, wc = w & 1;
  const int m0 = blockIdx.y * 128, n0 = blockIdx.x * 128;

  f32x4 acc[4][4] = {};

  for (int k0 = 0; k0 < K; k0 += 32) {
    __syncthreads();
#pragma unroll
    for (int p = 0; p < 2; ++p) {
      int id = p * 256 + tid;
      int row = id >> 2, q = id & 3;
      gld_lds16(P + (size_t)(m0 + row) * lda + k0 + q * 8, As + id * 8);
      gld_lds16(B + (size_t)(n0 + row) * ldb + k0 + q * 8, Bs + id * 8);
    }
    __syncthreads();
    f16x8 af[4], bfv[4];
#pragma unroll
    for (int i = 0; i < 4; ++i)
      af[i] = *(const f16x8*)(As + (wr * 64 + i * 16 + (lane & 15)) * 32 + (lane >> 4) * 8);
#pragma unroll
    for (int i = 0; i < 4; ++i)
      bfv[i] = *(const f16x8*)(Bs + (wc * 64 + i * 16 + (lane & 15)) * 32 + (lane >> 4) * 8);
#pragma unroll
    for (int i = 0; i < 4; ++i)
#pragma unroll
      for (int j = 0; j < 4; ++j)
        acc[i][j] = __builtin_amdgcn_mfma_f32_16x16x32_f16(af[i], bfv[j], acc[i][j], 0, 0, 0);
  }

#pragma unroll
  for (int i = 0; i < 4; ++i) {
    int r0 = m0 + wr * 64 + i * 16 + (lane >> 4) * 4;
#pragma unroll
    for (int e = 0; e < 4; ++e) {
      float scl = 0.25f / l[r0 + e];
#pragma unroll
      for (int j = 0; j < 4; ++j) {
        int c = n0 + wc * 64 + j * 16 + (lane & 15);
        C[(size_t)(r0 + e) * ldc + c] += acc[i][j][e] * scl;
      }
    }
  }
}

// partial row & col max of S (4096x4096 f32), 128x128 tiles, into ordered-uint arrays
__global__ __launch_bounds__(256)
void smax2d(const float* __restrict__ S, u32* __restrict__ rowm_u, u32* __restrict__ colm_u)
{
  __shared__ u32 rmax[128], cmax[128];
  const int tid = threadIdx.x;
  const int n0 = blockIdx.y * 128, m0 = blockIdx.x * 128;
  if (tid < 128) { rmax[tid] = 0u; cmax[tid] = 0u; }
  __syncthreads();
  const int rb = tid >> 5, c4 = (tid & 31) * 4;
  float cm0 = -3e38f, cm1 = -3e38f, cm2 = -3e38f, cm3 = -3e38f;
#pragma unroll
  for (int it = 0; it < 16; ++it) {
    int r = it * 8 + rb;
    f32x4 v = *(const f32x4*)(S + (size_t)(n0 + r) * NT + m0 + c4);
    cm0 = fmaxf(cm0, v[0]); cm1 = fmaxf(cm1, v[1]);
    cm2 = fmaxf(cm2, v[2]); cm3 = fmaxf(cm3, v[3]);
    float rm = fmaxf(fmaxf(v[0], v[1]), fmaxf(v[2], v[3]));
    atomicMax(&rmax[r], enc_ord(rm));
  }
  atomicMax(&cmax[c4 + 0], enc_ord(cm0));
  atomicMax(&cmax[c4 + 1], enc_ord(cm1));
  atomicMax(&cmax[c4 + 2], enc_ord(cm2));
  atomicMax(&cmax[c4 + 3], enc_ord(cm3));
  __syncthreads();
  if (tid < 128) {
    atomicMax(rowm_u + n0 + tid, rmax[tid]);
    atomicMax(colm_u + m0 + tid, cmax[tid]);
  }
}

// P[n,:] = exp(S[n,:]-rowmax[n]) f16; rowl[n] = sum
__global__ __launch_bounds__(256)
void rowP(const float* __restrict__ S, const u32* __restrict__ rowm_u,
          u16* __restrict__ P, float* __restrict__ rowl)
{
  const int n = blockIdx.x, tid = threadIdx.x;
  const float m = dec_ord(rowm_u[n]);
  const float* row = S + (size_t)n * NT;
  u16* prow = P + (size_t)n * NT;
  float s = 0.f;
#pragma unroll
  for (int it = 0; it < 4; ++it) {
    int idx = it * 1024 + tid * 4;
    f32x4 v = *(const f32x4*)(row + idx);
    float p0 = __expf(v[0] - m), p1 = __expf(v[1] - m);
    float p2 = __expf(v[2] - m), p3 = __expf(v[3] - m);
    s += (p0 + p1) + (p2 + p3);
    u16x4 pk; pk[0] = f2h(p0); pk[1] = f2h(p1); pk[2] = f2h(p2); pk[3] = f2h(p3);
    *(u16x4*)(prow + idx) = pk;
  }
#pragma unroll
  for (int o = 32; o; o >>= 1) s += __shfl_xor(s, o);
  __shared__ float sl[4];
  if ((tid & 63) == 0) sl[tid >> 6] = s;
  __syncthreads();
  if (tid == 0) rowl[n] = sl[0] + sl[1] + sl[2] + sl[3];
}

// PT[m,n] = exp(S[n,m]-colmax[m]) f16 (transposed write); psum[seg][m] partial col sums
__global__ __launch_bounds__(256)
void colPT(const float* __restrict__ S, const u32* __restrict__ colm_u,
           u16* __restrict__ PT, float* __restrict__ psum)
{
  __shared__ u16 T[128][132];
  __shared__ float cms[128];
  __shared__ float ps[8][128];
  const int tid = threadIdx.x;
  const int m0 = blockIdx.x * 128, n0 = blockIdx.y * 128;
  if (tid < 128) cms[tid] = dec_ord(colm_u[m0 + tid]);
  __syncthreads();
  const int rb = tid >> 5, c4 = (tid & 31) * 4;
  float s0 = 0.f, s1 = 0.f, s2 = 0.f, s3 = 0.f;
  const float q0 = cms[c4], q1 = cms[c4 + 1], q2 = cms[c4 + 2], q3 = cms[c4 + 3];
#pragma unroll
  for (int it = 0; it < 16; ++it) {
    int r = it * 8 + rb;
    f32x4 v = *(const f32x4*)(S + (size_t)(n0 + r) * NT + m0 + c4);
    float p0 = __expf(v[0] - q0), p1 = __expf(v[1] - q1);
    float p2 = __expf(v[2] - q2), p3 = __expf(v[3] - q3);
    s0 += p0; s1 += p1; s2 += p2; s3 += p3;
    u16x4 pk; pk[0] = f2h(p0); pk[1] = f2h(p1); pk[2] = f2h(p2); pk[3] = f2h(p3);
    *(u16x4*)&T[r][c4] = pk;
  }
  ps[rb][c4] = s0; ps[rb][c4 + 1] = s1; ps[rb][c4 + 2] = s2; ps[rb][c4 + 3] = s3;
  __syncthreads();
  if (tid < 128) {
    float s = 0.f;
#pragma unroll
    for (int g = 0; g < 8; ++g) s += ps[g][tid];
    psum[(size_t)blockIdx.y * NT + m0 + tid] = s;
  }
#pragma unroll
  for (int it = 0; it < 8; ++it) {
    int ml = it * 16 + (tid >> 4), n8 = (tid & 15) * 8;
    u16x8 o;
#pragma unroll
    for (int j = 0; j < 8; ++j) o[j] = T[n8 + j][ml];
    *(u16x8*)(PT + (size_t)(m0 + ml) * NT + n0 + n8) = o;
  }
}

// csum[m] = sum over 32 segs of psum[seg][m]
__global__ __launch_bounds__(256)
void csum_reduce(const float* __restrict__ psum, float* __restrict__ csum)
{
  int m = blockIdx.x * 256 + threadIdx.x;
  float s = 0.f;
#pragma unroll
  for (int g = 0; g < 32; ++g) s += psum[(size_t)g * NT + m];
  csum[m] = s;
}

__global__ __launch_bounds__(256)
void cast_f32_f16(const float* __restrict__ in, u16* __restrict__ out, int n)
{
  int i = (blockIdx.x * 256 + threadIdx.x) * 8;
  if (i >= n) return;
  f32x4 a = *(const f32x4*)(in + i), b = *(const f32x4*)(in + i + 4);
  u16x8 s;
  s[0] = f2h(a[0]); s[1] = f2h(a[1]); s[2] = f2h(a[2]); s[3] = f2h(a[3]);
  s[4] = f2h(b[0]); s[5] = f2h(b[1]); s[6] = f2h(b[2]); s[7] = f2h(b[3]);
  *(u16x8*)(out + i) = s;
}

// out[c][r] = f16(in[r][c]);  64x64 tiles
__global__ __launch_bounds__(256)
void transpose_cast_f32(const float* __restrict__ in, int ldi,
                        u16* __restrict__ out, int ldo)
{
  __shared__ u16 t[64][72];
  int r0 = blockIdx.x * 64, c0 = blockIdx.y * 64;
  int t8 = threadIdx.x & 7, rr = threadIdx.x >> 3;
#pragma unroll
  for (int p = 0; p < 2; ++p) {
    int r = rr + p * 32;
    const float* src = in + (size_t)(r0 + r) * ldi + c0 + t8 * 8;
    f32x4 a = *(const f32x4*)src, b = *(const f32x4*)(src + 4);
    u16x8 s;
    s[0] = f2h(a[0]); s[1] = f2h(a[1]); s[2] = f2h(a[2]); s[3] = f2h(a[3]);
    s[4] = f2h(b[0]); s[5] = f2h(b[1]); s[6] = f2h(b[2]); s[7] = f2h(b[3]);
    *(u16x8*)&t[r][t8 * 8] = s;
  }
  __syncthreads();
#pragma unroll
  for (int p = 0; p < 2; ++p) {
    int c = rr + p * 32;
    u16x8 s;
#pragma unroll
    for (int j = 0; j < 8; ++j) s[j] = t[t8 * 8 + j][c];
    *(u16x8*)(out + (size_t)(c0 + c) * ldo + r0 + t8 * 8) = s;
  }
}

__global__ __launch_bounds__(256)
void transpose_f16(const u16* __restrict__ in, int ldi,
                   u16* __restrict__ out, int ldo)
{
  __shared__ u16 t[64][72];
  int r0 = blockIdx.x * 64, c0 = blockIdx.y * 64;
  int t8 = threadIdx.x & 7, rr = threadIdx.x >> 3;
#pragma unroll
  for (int p = 0; p < 2; ++p) {
    int r = rr + p * 32;
    *(u16x8*)&t[r][t8 * 8] = *(const u16x8*)(in + (size_t)(r0 + r) * ldi + c0 + t8 * 8);
  }
  __syncthreads();
#pragma unroll
  for (int p = 0; p < 2; ++p) {
    int c = rr + p * 32;
    u16x8 s;
#pragma unroll
    for (int j = 0; j < 8; ++j) s[j] = t[t8 * 8 + j][c];
    *(u16x8*)(out + (size_t)(c0 + c) * ldo + r0 + t8 * 8) = s;
  }
}

extern "C" void kernel_launch(void* const* d_in, const int* in_sizes, int n_in,
                              void* d_out, int out_size, void* d_ws, size_t ws_size,
                              hipStream_t stream)
{
  const float* x_k    = (const float*)d_in[0];
  const float* x_q    = (const float*)d_in[1];
  const float* k_w    = (const float*)d_in[2];
  const float* q_w    = (const float*)d_in[3];
  const float* attn_w = (const float*)d_in[4];
  const float* proj_w = (const float*)d_in[5];
  float* out0 = (float*)d_out;                 // doubles as aggk accumulator
  float* out1 = out0 + (size_t)NT * D;         // doubles as aggq accumulator

  char* wptr = (char*)d_ws;
  auto alloc = [&](size_t bytes) { char* p = wptr; wptr += (bytes + 255) & ~(size_t)255; return p; };
  u16*   pb     = (u16*)  alloc((size_t)D * D * 2);
  u16*   pbT    = (u16*)  alloc((size_t)D * D * 2);
  u16*   XKall  = (u16*)  alloc((size_t)NT * NH * D * 2);   // [4096][2048]
  u16*   XKTall = (u16*)  alloc((size_t)NT * NH * D * 2);   // [2048][4096]
  u16*   XQTall = (u16*)  alloc((size_t)NT * NH * D * 2);   // [2048][4096]
  u16*   Kpall  = (u16*)  alloc((size_t)NH * NT * D * 2);   // [4][4096][512]
  u16*   Pbuf   = (u16*)  alloc((size_t)NT * NT * 2);       // P1 then P2T per head
  u32*   rowm_u = (u32*)  alloc((size_t)NT * 4);
  u32*   colm_u = (u32*)  alloc((size_t)NT * 4);            // contiguous with rowm_u
  float* rowl   = (float*)alloc((size_t)NT * 4);
  float* csum   = (float*)alloc((size_t)NT * 4);
  float* psum   = (float*)alloc((size_t)32 * NT * 4);
  char*  Sreg   = alloc((size_t)NT * NT * 4);               // S f32; prep scratch aliased below
  float* S      = (float*)Sreg;
  // prep-only scratch aliased into the (not yet used) S region
  char* sp = Sreg;
  auto salloc = [&](size_t bytes) { char* p = sp; sp += (bytes + 255) & ~(size_t)255; return p; };
  u16* xkb   = (u16*)salloc((size_t)NT * D * 2);
  u16* xqb   = (u16*)salloc((size_t)NT * D * 2);
  u16* kwb   = (u16*)salloc((size_t)NH * D * D * 2);
  u16* qwb   = (u16*)salloc((size_t)NH * D * D * 2);
  u16* Abf   = (u16*)salloc((size_t)NH * D * D * 2);
  u16* XQall = (u16*)salloc((size_t)NT * NH * D * 2);

  // ---- prep: casts + projections (all heads batched) ----
  cast_f32_f16<<<NT * D / 2048, 256, 0, stream>>>(x_k, xkb, NT * D);
  cast_f32_f16<<<NT * D / 2048, 256, 0, stream>>>(x_q, xqb, NT * D);
  cast_f32_f16<<<NH * D * D / 2048, 256, 0, stream>>>(k_w, kwb, NH * D * D);
  cast_f32_f16<<<NH * D * D / 2048, 256, 0, stream>>>(q_w, qwb, NH * D * D);
  cast_f32_f16<<<NH * D * D / 2048, 256, 0, stream>>>(attn_w, Abf, NH * D * D);
  cast_f32_f16<<<D * D / 2048, 256, 0, stream>>>(proj_w, pb, D * D);
  transpose_cast_f32<<<dim3(D / 64, D / 64), 256, 0, stream>>>(proj_w, D, pbT, D);

  // XKall = xkb @ kwb^T  [4096][2048];  XQall likewise
  gemm_bt<OUT_F16><<<dim3(NH * D / 128, NT / 128), 256, 0, stream>>>(
      xkb, D, 0, kwb, D, 0, XKall, NH * D, 0, nullptr, D);
  gemm_bt<OUT_F16><<<dim3(NH * D / 128, NT / 128), 256, 0, stream>>>(
      xqb, D, 0, qwb, D, 0, XQall, NH * D, 0, nullptr, D);
  transpose_f16<<<dim3(NT / 64, NH * D / 64), 256, 0, stream>>>(XKall, NH * D, XKTall, NT);
  transpose_f16<<<dim3(NT / 64, NH * D / 64), 256, 0, stream>>>(XQall, NH * D, XQTall, NT);
  // Kpall[h] = XQ_h @ A_h^T   (batched over z)
  gemm_bt<OUT_F16><<<dim3(D / 128, NT / 128, NH), 256, 0, stream>>>(
      XQall, NH * D, (size_t)D, Abf, D, (size_t)D * D, Kpall, D, (size_t)NT * D, nullptr, D);

  hipMemsetAsync(d_out, 0, (size_t)2 * NT * D * 4, stream);   // aggk+aggq accumulators

  // ---- per-head ----
  for (int h = 0; h < NH; ++h) {
    const u16* XKh  = XKall + (size_t)h * D;          // lda 2048
    const u16* XKTh = XKTall + (size_t)h * D * NT;    // ldb 4096
    const u16* XQTh = XQTall + (size_t)h * D * NT;
    const u16* Kph  = Kpall + (size_t)h * NT * D;     // ldb 512

    // S = XK_h @ Kp_h^T   [4096][4096] f32
    gemm_bt<OUT_F32><<<dim3(NT / 128, NT / 128), 256, 0, stream>>>(
        XKh, NH * D, 0, Kph, D, 0, S, NT, 0, nullptr, D);

    hipMemsetAsync(rowm_u, 0, (size_t)NT * 4 * 2, stream);    // rowm_u + colm_u
    smax2d<<<dim3(NT / 128, NT / 128), 256, 0, stream>>>(S, rowm_u, colm_u);

    // dir1: P1 = exp(S - rowmax), aggk += P1 @ XQ_h / (4*rowsum)
    rowP<<<NT, 256, 0, stream>>>(S, rowm_u, Pbuf, rowl);
    gemm_ps<<<dim3(D / 128, NT / 128), 256, 0, stream>>>(Pbuf, NT, XQTh, NT, out0, D, rowl, NT);

    // dir2: P2T = exp(S^T - colmax), aggq += P2T @ XK_h / (4*colsum)
    colPT<<<dim3(NT / 128, NT / 128), 256, 0, stream>>>(S, colm_u, Pbuf, psum);
    csum_reduce<<<NT / 256, 256, 0, stream>>>(psum, csum);
    gemm_ps<<<dim3(D / 128, NT / 128), 256, 0, stream>>>(Pbuf, NT, XKTh, NT, out1, D, csum, NT);
  }

  // ---- final projections + residual ----
  u16* kf16 = Pbuf;
  u16* qf16 = Pbuf + (size_t)NT * D;
  cast_f32_f16<<<NT * D / 2048, 256, 0, stream>>>(out0, kf16, NT * D);
  cast_f32_f16<<<NT * D / 2048, 256, 0, stream>>>(out1, qf16, NT * D);
  gemm_bt<OUT_RES><<<dim3(D / 128, NT / 128), 256, 0, stream>>>(
      kf16, D, 0, pb, D, 0, out0, D, 0, x_k, D);
  gemm_bt<OUT_RES><<<dim3(D / 128, NT / 128), 256, 0, stream>>>(
      qf16, D, 0, pbT, D, 0, out1, D, 0, x_q, D);
}

// Round 4
// 807.953 us; speedup vs baseline: 2.1540x; 1.4715x over previous
//
#include <hip/hip_runtime.h>
#include <stdint.h>

#define DEVI __device__ __forceinline__

typedef unsigned short u16;
typedef unsigned int u32;
typedef __attribute__((ext_vector_type(4))) unsigned short u16x4;
typedef __attribute__((ext_vector_type(8))) unsigned short u16x8;
typedef __attribute__((ext_vector_type(4))) float f32x4;
typedef __attribute__((ext_vector_type(8))) _Float16 f16x8;

static constexpr int NT = 4096;   // tokens
static constexpr int D  = 512;    // channels per head
static constexpr int NH = 4;      // heads
static constexpr int KS = 4;      // split-K factor for PV GEMMs

DEVI u16 f2h(float f) {
  _Float16 h = (_Float16)f;
  union { _Float16 h; u16 u; } v; v.h = h;
  return v.u;
}

// order-preserving float<->uint for atomicMax on floats
DEVI u32 enc_ord(float f) {
  u32 u = __float_as_uint(f);
  return (u & 0x80000000u) ? ~u : (u | 0x80000000u);
}
DEVI float dec_ord(u32 k) {
  u32 u = (k & 0x80000000u) ? (k ^ 0x80000000u) : ~k;
  return __uint_as_float(u);
}

DEVI void gld_lds16(const u16* g, u16* l) {
  __builtin_amdgcn_global_load_lds((const __attribute__((address_space(1))) void*)g,
                                   (__attribute__((address_space(3))) void*)l, 16, 0, 0);
}

enum { OUT_F32 = 0, OUT_F16 = 2, OUT_RES = 3 };

// C[M,N] = A[M,K] @ B[N,K]^T  (f16 in, f32 acc). 128x128 tile, BK=32, 4 waves.
// Optional batch via blockIdx.z with element strides zsA/zsB/zsC.
template<int OUT>
__global__ __launch_bounds__(256)
void gemm_bt(const u16* __restrict__ A, int lda, size_t zsA,
             const u16* __restrict__ B, int ldb, size_t zsB,
             void* __restrict__ Cp, int ldc, size_t zsC,
             const float* __restrict__ res, int K)
{
  __shared__ u16 As[128 * 32];
  __shared__ u16 Bs[128 * 32];
  A += blockIdx.z * zsA;
  B += blockIdx.z * zsB;
  const int tid = threadIdx.x;
  const int lane = tid & 63, w = tid >> 6;
  const int wr = w >> 1, wc = w & 1;
  const int m0 = blockIdx.y * 128, n0 = blockIdx.x * 128;

  f32x4 acc[4][4] = {};

  for (int k0 = 0; k0 < K; k0 += 32) {
    __syncthreads();
#pragma unroll
    for (int p = 0; p < 2; ++p) {
      int id = p * 256 + tid;
      int row = id >> 2, q = id & 3;
      gld_lds16(A + (size_t)(m0 + row) * lda + k0 + q * 8, As + id * 8);
      gld_lds16(B + (size_t)(n0 + row) * ldb + k0 + q * 8, Bs + id * 8);
    }
    __syncthreads();
    f16x8 af[4], bfv[4];
#pragma unroll
    for (int i = 0; i < 4; ++i)
      af[i] = *(const f16x8*)(As + (wr * 64 + i * 16 + (lane & 15)) * 32 + (lane >> 4) * 8);
#pragma unroll
    for (int i = 0; i < 4; ++i)
      bfv[i] = *(const f16x8*)(Bs + (wc * 64 + i * 16 + (lane & 15)) * 32 + (lane >> 4) * 8);
#pragma unroll
    for (int i = 0; i < 4; ++i)
#pragma unroll
      for (int j = 0; j < 4; ++j)
        acc[i][j] = __builtin_amdgcn_mfma_f32_16x16x32_f16(af[i], bfv[j], acc[i][j], 0, 0, 0);
  }

#pragma unroll
  for (int i = 0; i < 4; ++i) {
    int r0 = m0 + wr * 64 + i * 16 + (lane >> 4) * 4;
#pragma unroll
    for (int j = 0; j < 4; ++j) {
      int c = n0 + wc * 64 + j * 16 + (lane & 15);
#pragma unroll
      for (int e = 0; e < 4; ++e) {
        size_t idx = blockIdx.z * zsC + (size_t)(r0 + e) * ldc + c;
        float v = acc[i][j][e];
        if (OUT == OUT_F32) ((float*)Cp)[idx] = v;
        if (OUT == OUT_F16) ((u16*)Cp)[idx] = f2h(v);
        if (OUT == OUT_RES) ((float*)Cp)[idx] = res[idx] + v;
      }
    }
  }
}

// partial[z][M][512] = (0.25/l[m]) * (P[M, z*Ksl : (z+1)*Ksl] @ B[:, z*Ksl:...]^T)
// split-K over blockIdx.z; pure store (deterministic reduce afterwards)
__global__ __launch_bounds__(256)
void gemm_ps(const u16* __restrict__ P, int lda,
             const u16* __restrict__ B, int ldb,
             float* __restrict__ partial,
             const float* __restrict__ l, int Ksl)
{
  __shared__ u16 As[128 * 32];
  __shared__ u16 Bs[128 * 32];
  const int tid = threadIdx.x;
  const int lane = tid & 63, w = tid >> 6;
  const int wr = w >> 1, wc = w & 1;
  const int m0 = blockIdx.y * 128, n0 = blockIdx.x * 128;
  const int kb = blockIdx.z * Ksl;

  f32x4 acc[4][4] = {};

  for (int k0 = 0; k0 < Ksl; k0 += 32) {
    __syncthreads();
#pragma unroll
    for (int p = 0; p < 2; ++p) {
      int id = p * 256 + tid;
      int row = id >> 2, q = id & 3;
      gld_lds16(P + (size_t)(m0 + row) * lda + kb + k0 + q * 8, As + id * 8);
      gld_lds16(B + (size_t)(n0 + row) * ldb + kb + k0 + q * 8, Bs + id * 8);
    }
    __syncthreads();
    f16x8 af[4], bfv[4];
#pragma unroll
    for (int i = 0; i < 4; ++i)
      af[i] = *(const f16x8*)(As + (wr * 64 + i * 16 + (lane & 15)) * 32 + (lane >> 4) * 8);
#pragma unroll
    for (int i = 0; i < 4; ++i)
      bfv[i] = *(const f16x8*)(Bs + (wc * 64 + i * 16 + (lane & 15)) * 32 + (lane >> 4) * 8);
#pragma unroll
    for (int i = 0; i < 4; ++i)
#pragma unroll
      for (int j = 0; j < 4; ++j)
        acc[i][j] = __builtin_amdgcn_mfma_f32_16x16x32_f16(af[i], bfv[j], acc[i][j], 0, 0, 0);
  }

  float* out = partial + (size_t)blockIdx.z * NT * D;
#pragma unroll
  for (int i = 0; i < 4; ++i) {
    int r0 = m0 + wr * 64 + i * 16 + (lane >> 4) * 4;
#pragma unroll
    for (int e = 0; e < 4; ++e) {
      float scl = 0.25f / l[r0 + e];
#pragma unroll
      for (int j = 0; j < 4; ++j) {
        int c = n0 + wc * 64 + j * 16 + (lane & 15);
        out[(size_t)(r0 + e) * D + c] = acc[i][j][e] * scl;
      }
    }
  }
}

// out0 += sum_z pk[z]; out1 += sum_z pq[z]   (deterministic order)
__global__ __launch_bounds__(256)
void reduce_ps(const float* __restrict__ pk, const float* __restrict__ pq,
               float* __restrict__ out0, float* __restrict__ out1)
{
  const size_t i = ((size_t)blockIdx.x * 256 + threadIdx.x) * 4;
  const size_t zs = (size_t)NT * D;
  f32x4 s = *(const f32x4*)(pk + i);
#pragma unroll
  for (int z = 1; z < KS; ++z) s += *(const f32x4*)(pk + z * zs + i);
  f32x4 o = *(const f32x4*)(out0 + i);
  *(f32x4*)(out0 + i) = o + s;
  f32x4 t = *(const f32x4*)(pq + i);
#pragma unroll
  for (int z = 1; z < KS; ++z) t += *(const f32x4*)(pq + z * zs + i);
  f32x4 p = *(const f32x4*)(out1 + i);
  *(f32x4*)(out1 + i) = p + t;
}

// partial row & col max of S (4096x4096 f32), 128x128 tiles, into ordered-uint arrays
__global__ __launch_bounds__(256)
void smax2d(const float* __restrict__ S, u32* __restrict__ rowm_u, u32* __restrict__ colm_u)
{
  __shared__ u32 rmax[128], cmax[128];
  const int tid = threadIdx.x;
  const int n0 = blockIdx.y * 128, m0 = blockIdx.x * 128;
  if (tid < 128) { rmax[tid] = 0u; cmax[tid] = 0u; }
  __syncthreads();
  const int rb = tid >> 5, c4 = (tid & 31) * 4;
  float cm0 = -3e38f, cm1 = -3e38f, cm2 = -3e38f, cm3 = -3e38f;
#pragma unroll
  for (int it = 0; it < 16; ++it) {
    int r = it * 8 + rb;
    f32x4 v = *(const f32x4*)(S + (size_t)(n0 + r) * NT + m0 + c4);
    cm0 = fmaxf(cm0, v[0]); cm1 = fmaxf(cm1, v[1]);
    cm2 = fmaxf(cm2, v[2]); cm3 = fmaxf(cm3, v[3]);
    float rm = fmaxf(fmaxf(v[0], v[1]), fmaxf(v[2], v[3]));
    atomicMax(&rmax[r], enc_ord(rm));
  }
  atomicMax(&cmax[c4 + 0], enc_ord(cm0));
  atomicMax(&cmax[c4 + 1], enc_ord(cm1));
  atomicMax(&cmax[c4 + 2], enc_ord(cm2));
  atomicMax(&cmax[c4 + 3], enc_ord(cm3));
  __syncthreads();
  if (tid < 128) {
    atomicMax(rowm_u + n0 + tid, rmax[tid]);
    atomicMax(colm_u + m0 + tid, cmax[tid]);
  }
}

// P[n,:] = exp(S[n,:]-rowmax[n]) f16; rowl[n] = sum
__global__ __launch_bounds__(256)
void rowP(const float* __restrict__ S, const u32* __restrict__ rowm_u,
          u16* __restrict__ P, float* __restrict__ rowl)
{
  const int n = blockIdx.x, tid = threadIdx.x;
  const float m = dec_ord(rowm_u[n]);
  const float* row = S + (size_t)n * NT;
  u16* prow = P + (size_t)n * NT;
  float s = 0.f;
#pragma unroll
  for (int it = 0; it < 4; ++it) {
    int idx = it * 1024 + tid * 4;
    f32x4 v = *(const f32x4*)(row + idx);
    float p0 = __expf(v[0] - m), p1 = __expf(v[1] - m);
    float p2 = __expf(v[2] - m), p3 = __expf(v[3] - m);
    s += (p0 + p1) + (p2 + p3);
    u16x4 pk; pk[0] = f2h(p0); pk[1] = f2h(p1); pk[2] = f2h(p2); pk[3] = f2h(p3);
    *(u16x4*)(prow + idx) = pk;
  }
#pragma unroll
  for (int o = 32; o; o >>= 1) s += __shfl_xor(s, o);
  __shared__ float sl[4];
  if ((tid & 63) == 0) sl[tid >> 6] = s;
  __syncthreads();
  if (tid == 0) rowl[n] = sl[0] + sl[1] + sl[2] + sl[3];
}

// PT[m,n] = exp(S[n,m]-colmax[m]) f16 (transposed write); psum[seg][m] partial col sums
__global__ __launch_bounds__(256)
void colPT(const float* __restrict__ S, const u32* __restrict__ colm_u,
           u16* __restrict__ PT, float* __restrict__ psum)
{
  __shared__ u16 T[128][132];
  __shared__ float cms[128];
  __shared__ float ps[8][128];
  const int tid = threadIdx.x;
  const int m0 = blockIdx.x * 128, n0 = blockIdx.y * 128;
  if (tid < 128) cms[tid] = dec_ord(colm_u[m0 + tid]);
  __syncthreads();
  const int rb = tid >> 5, c4 = (tid & 31) * 4;
  float s0 = 0.f, s1 = 0.f, s2 = 0.f, s3 = 0.f;
  const float q0 = cms[c4], q1 = cms[c4 + 1], q2 = cms[c4 + 2], q3 = cms[c4 + 3];
#pragma unroll
  for (int it = 0; it < 16; ++it) {
    int r = it * 8 + rb;
    f32x4 v = *(const f32x4*)(S + (size_t)(n0 + r) * NT + m0 + c4);
    float p0 = __expf(v[0] - q0), p1 = __expf(v[1] - q1);
    float p2 = __expf(v[2] - q2), p3 = __expf(v[3] - q3);
    s0 += p0; s1 += p1; s2 += p2; s3 += p3;
    u16x4 pk; pk[0] = f2h(p0); pk[1] = f2h(p1); pk[2] = f2h(p2); pk[3] = f2h(p3);
    *(u16x4*)&T[r][c4] = pk;
  }
  ps[rb][c4] = s0; ps[rb][c4 + 1] = s1; ps[rb][c4 + 2] = s2; ps[rb][c4 + 3] = s3;
  __syncthreads();
  if (tid < 128) {
    float s = 0.f;
#pragma unroll
    for (int g = 0; g < 8; ++g) s += ps[g][tid];
    psum[(size_t)blockIdx.y * NT + m0 + tid] = s;
  }
#pragma unroll
  for (int it = 0; it < 8; ++it) {
    int ml = it * 16 + (tid >> 4), n8 = (tid & 15) * 8;
    u16x8 o;
#pragma unroll
    for (int j = 0; j < 8; ++j) o[j] = T[n8 + j][ml];
    *(u16x8*)(PT + (size_t)(m0 + ml) * NT + n0 + n8) = o;
  }
}

// csum[m] = sum over 32 segs of psum[seg][m]
__global__ __launch_bounds__(256)
void csum_reduce(const float* __restrict__ psum, float* __restrict__ csum)
{
  int m = blockIdx.x * 256 + threadIdx.x;
  float s = 0.f;
#pragma unroll
  for (int g = 0; g < 32; ++g) s += psum[(size_t)g * NT + m];
  csum[m] = s;
}

__global__ __launch_bounds__(256)
void cast_f32_f16(const float* __restrict__ in, u16* __restrict__ out, int n)
{
  int i = (blockIdx.x * 256 + threadIdx.x) * 8;
  if (i >= n) return;
  f32x4 a = *(const f32x4*)(in + i), b = *(const f32x4*)(in + i + 4);
  u16x8 s;
  s[0] = f2h(a[0]); s[1] = f2h(a[1]); s[2] = f2h(a[2]); s[3] = f2h(a[3]);
  s[4] = f2h(b[0]); s[5] = f2h(b[1]); s[6] = f2h(b[2]); s[7] = f2h(b[3]);
  *(u16x8*)(out + i) = s;
}

// out[c][r] = f16(in[r][c]);  64x64 tiles
__global__ __launch_bounds__(256)
void transpose_cast_f32(const float* __restrict__ in, int ldi,
                        u16* __restrict__ out, int ldo)
{
  __shared__ u16 t[64][72];
  int r0 = blockIdx.x * 64, c0 = blockIdx.y * 64;
  int t8 = threadIdx.x & 7, rr = threadIdx.x >> 3;
#pragma unroll
  for (int p = 0; p < 2; ++p) {
    int r = rr + p * 32;
    const float* src = in + (size_t)(r0 + r) * ldi + c0 + t8 * 8;
    f32x4 a = *(const f32x4*)src, b = *(const f32x4*)(src + 4);
    u16x8 s;
    s[0] = f2h(a[0]); s[1] = f2h(a[1]); s[2] = f2h(a[2]); s[3] = f2h(a[3]);
    s[4] = f2h(b[0]); s[5] = f2h(b[1]); s[6] = f2h(b[2]); s[7] = f2h(b[3]);
    *(u16x8*)&t[r][t8 * 8] = s;
  }
  __syncthreads();
#pragma unroll
  for (int p = 0; p < 2; ++p) {
    int c = rr + p * 32;
    u16x8 s;
#pragma unroll
    for (int j = 0; j < 8; ++j) s[j] = t[t8 * 8 + j][c];
    *(u16x8*)(out + (size_t)(c0 + c) * ldo + r0 + t8 * 8) = s;
  }
}

__global__ __launch_bounds__(256)
void transpose_f16(const u16* __restrict__ in, int ldi,
                   u16* __restrict__ out, int ldo)
{
  __shared__ u16 t[64][72];
  int r0 = blockIdx.x * 64, c0 = blockIdx.y * 64;
  int t8 = threadIdx.x & 7, rr = threadIdx.x >> 3;
#pragma unroll
  for (int p = 0; p < 2; ++p) {
    int r = rr + p * 32;
    *(u16x8*)&t[r][t8 * 8] = *(const u16x8*)(in + (size_t)(r0 + r) * ldi + c0 + t8 * 8);
  }
  __syncthreads();
#pragma unroll
  for (int p = 0; p < 2; ++p) {
    int c = rr + p * 32;
    u16x8 s;
#pragma unroll
    for (int j = 0; j < 8; ++j) s[j] = t[t8 * 8 + j][c];
    *(u16x8*)(out + (size_t)(c0 + c) * ldo + r0 + t8 * 8) = s;
  }
}

extern "C" void kernel_launch(void* const* d_in, const int* in_sizes, int n_in,
                              void* d_out, int out_size, void* d_ws, size_t ws_size,
                              hipStream_t stream)
{
  const float* x_k    = (const float*)d_in[0];
  const float* x_q    = (const float*)d_in[1];
  const float* k_w    = (const float*)d_in[2];
  const float* q_w    = (const float*)d_in[3];
  const float* attn_w = (const float*)d_in[4];
  const float* proj_w = (const float*)d_in[5];
  float* out0 = (float*)d_out;                 // doubles as aggk accumulator
  float* out1 = out0 + (size_t)NT * D;         // doubles as aggq accumulator

  char* wptr = (char*)d_ws;
  auto alloc = [&](size_t bytes) { char* p = wptr; wptr += (bytes + 255) & ~(size_t)255; return p; };
  u16*   pb     = (u16*)  alloc((size_t)D * D * 2);
  u16*   pbT    = (u16*)  alloc((size_t)D * D * 2);
  u16*   XKall  = (u16*)  alloc((size_t)NT * NH * D * 2);   // [4096][2048]
  u16*   XKTall = (u16*)  alloc((size_t)NT * NH * D * 2);   // [2048][4096]
  u16*   XQTall = (u16*)  alloc((size_t)NT * NH * D * 2);   // [2048][4096]
  u16*   Kpall  = (u16*)  alloc((size_t)NH * NT * D * 2);   // [4][4096][512]
  u16*   Pbuf   = (u16*)  alloc((size_t)NT * NT * 2);       // P1 then P2T per head
  u32*   rowm_u = (u32*)  alloc((size_t)NT * 4);
  u32*   colm_u = (u32*)  alloc((size_t)NT * 4);            // contiguous with rowm_u
  float* rowl   = (float*)alloc((size_t)NT * 4);
  float* csum   = (float*)alloc((size_t)NT * 4);
  float* psum   = (float*)alloc((size_t)32 * NT * 4);
  float* partK  = (float*)alloc((size_t)KS * NT * D * 4);   // split-K partials (dir1)
  char*  Sreg   = alloc((size_t)NT * NT * 4);               // S f32; prep scratch aliased below
  float* S      = (float*)Sreg;
  float* partQ  = (float*)Sreg;                             // aliases S (dead after colPT)
  // prep-only scratch aliased into the (not yet used) S region
  char* sp = Sreg;
  auto salloc = [&](size_t bytes) { char* p = sp; sp += (bytes + 255) & ~(size_t)255; return p; };
  u16* xkb   = (u16*)salloc((size_t)NT * D * 2);
  u16* xqb   = (u16*)salloc((size_t)NT * D * 2);
  u16* kwb   = (u16*)salloc((size_t)NH * D * D * 2);
  u16* qwb   = (u16*)salloc((size_t)NH * D * D * 2);
  u16* Abf   = (u16*)salloc((size_t)NH * D * D * 2);
  u16* XQall = (u16*)salloc((size_t)NT * NH * D * 2);

  // ---- prep: casts + projections (all heads batched) ----
  cast_f32_f16<<<NT * D / 2048, 256, 0, stream>>>(x_k, xkb, NT * D);
  cast_f32_f16<<<NT * D / 2048, 256, 0, stream>>>(x_q, xqb, NT * D);
  cast_f32_f16<<<NH * D * D / 2048, 256, 0, stream>>>(k_w, kwb, NH * D * D);
  cast_f32_f16<<<NH * D * D / 2048, 256, 0, stream>>>(q_w, qwb, NH * D * D);
  cast_f32_f16<<<NH * D * D / 2048, 256, 0, stream>>>(attn_w, Abf, NH * D * D);
  cast_f32_f16<<<D * D / 2048, 256, 0, stream>>>(proj_w, pb, D * D);
  transpose_cast_f32<<<dim3(D / 64, D / 64), 256, 0, stream>>>(proj_w, D, pbT, D);

  // XKall = xkb @ kwb^T  [4096][2048];  XQall likewise
  gemm_bt<OUT_F16><<<dim3(NH * D / 128, NT / 128), 256, 0, stream>>>(
      xkb, D, 0, kwb, D, 0, XKall, NH * D, 0, nullptr, D);
  gemm_bt<OUT_F16><<<dim3(NH * D / 128, NT / 128), 256, 0, stream>>>(
      xqb, D, 0, qwb, D, 0, XQall, NH * D, 0, nullptr, D);
  transpose_f16<<<dim3(NT / 64, NH * D / 64), 256, 0, stream>>>(XKall, NH * D, XKTall, NT);
  transpose_f16<<<dim3(NT / 64, NH * D / 64), 256, 0, stream>>>(XQall, NH * D, XQTall, NT);
  // Kpall[h] = XQ_h @ A_h^T   (batched over z)
  gemm_bt<OUT_F16><<<dim3(D / 128, NT / 128, NH), 256, 0, stream>>>(
      XQall, NH * D, (size_t)D, Abf, D, (size_t)D * D, Kpall, D, (size_t)NT * D, nullptr, D);

  hipMemsetAsync(d_out, 0, (size_t)2 * NT * D * 4, stream);   // aggk+aggq accumulators

  // ---- per-head ----
  for (int h = 0; h < NH; ++h) {
    const u16* XKh  = XKall + (size_t)h * D;          // lda 2048
    const u16* XKTh = XKTall + (size_t)h * D * NT;    // ldb 4096
    const u16* XQTh = XQTall + (size_t)h * D * NT;
    const u16* Kph  = Kpall + (size_t)h * NT * D;     // ldb 512

    // S = XK_h @ Kp_h^T   [4096][4096] f32
    gemm_bt<OUT_F32><<<dim3(NT / 128, NT / 128), 256, 0, stream>>>(
        XKh, NH * D, 0, Kph, D, 0, S, NT, 0, nullptr, D);

    hipMemsetAsync(rowm_u, 0, (size_t)NT * 4 * 2, stream);    // rowm_u + colm_u
    smax2d<<<dim3(NT / 128, NT / 128), 256, 0, stream>>>(S, rowm_u, colm_u);

    // dir1: P1 = exp(S - rowmax), partK[z] = P1_z @ XQ_h (scaled 0.25/rowsum)
    rowP<<<NT, 256, 0, stream>>>(S, rowm_u, Pbuf, rowl);
    gemm_ps<<<dim3(D / 128, NT / 128, KS), 256, 0, stream>>>(
        Pbuf, NT, XQTh, NT, partK, rowl, NT / KS);

    // dir2: P2T = exp(S^T - colmax), partQ[z] = P2T_z @ XK_h (scaled 0.25/colsum)
    colPT<<<dim3(NT / 128, NT / 128), 256, 0, stream>>>(S, colm_u, Pbuf, psum);
    csum_reduce<<<NT / 256, 256, 0, stream>>>(psum, csum);
    gemm_ps<<<dim3(D / 128, NT / 128, KS), 256, 0, stream>>>(
        Pbuf, NT, XKTh, NT, partQ, csum, NT / KS);

    // accumulate both directions into d_out (deterministic)
    reduce_ps<<<NT * D / 1024, 256, 0, stream>>>(partK, partQ, out0, out1);
  }

  // ---- final projections + residual ----
  u16* kf16 = Pbuf;
  u16* qf16 = Pbuf + (size_t)NT * D;
  cast_f32_f16<<<NT * D / 2048, 256, 0, stream>>>(out0, kf16, NT * D);
  cast_f32_f16<<<NT * D / 2048, 256, 0, stream>>>(out1, qf16, NT * D);
  gemm_bt<OUT_RES><<<dim3(D / 128, NT / 128), 256, 0, stream>>>(
      kf16, D, 0, pb, D, 0, out0, D, 0, x_k, D);
  gemm_bt<OUT_RES><<<dim3(D / 128, NT / 128), 256, 0, stream>>>(
      qf16, D, 0, pbT, D, 0, out1, D, 0, x_q, D);
}